// Round 2
// baseline (304.125 us; speedup 1.0000x reference)
//
#include <hip/hip_runtime.h>

#define HW_SHIFT 18               // H*W = 512*512 = 2^18
#define HW (1 << HW_SHIFT)
#define NC 6
#define NIC 3
#define EPS 1e-5f

__global__ __launch_bounds__(256) void aff_softmax_kernel(
    const float* __restrict__ x,
    const float* __restrict__ w1, const float* __restrict__ b1,
    const float* __restrict__ g1, const float* __restrict__ be1,
    const float* __restrict__ m1, const float* __restrict__ v1,
    const float* __restrict__ w2, const float* __restrict__ b2,
    const float* __restrict__ g2, const float* __restrict__ be2,
    const float* __restrict__ m2, const float* __restrict__ v2,
    float* __restrict__ out)
{
    const int g = blockIdx.x * blockDim.x + threadIdx.x;

    // ---- 4 pixels per thread: issue all 6 plane loads first (latency) ----
    const long p  = (long)g << 2;               // first pixel index
    const int  b  = (int)(p >> HW_SHIFT);       // batch
    const int  hw = (int)(p & (HW - 1));        // offset within plane
    const float* xb = x + ((long)b * NC << HW_SHIFT) + hw;

    // xp[i][c]: pixel i's channel-c value. Constant indices only -> registers.
    float xp[4][NC];
#pragma unroll
    for (int c = 0; c < NC; ++c) {
        const float4 v = *(const float4*)(xb + ((long)c << HW_SHIFT));
        xp[0][c] = v.x; xp[1][c] = v.y; xp[2][c] = v.z; xp[3][c] = v.w;
    }

    // ---- Fold BN1 into conv1, BN2 into conv2 (uniform scalars) ----
    float W1f[NIC][NC], B1f[NIC];
#pragma unroll
    for (int o = 0; o < NIC; ++o) {
        const float inv = g1[o] * rsqrtf(v1[o] + EPS);
        B1f[o] = b1[o] * inv + (be1[o] - m1[o] * inv);
#pragma unroll
        for (int c = 0; c < NC; ++c) W1f[o][c] = w1[o * NC + c] * inv;
    }
    float W2f[NC][NIC], B2f[NC];
#pragma unroll
    for (int o = 0; o < NC; ++o) {
        const float inv = g2[o] * rsqrtf(v2[o] + EPS);
        B2f[o] = b2[o] * inv + (be2[o] - m2[o] * inv);
#pragma unroll
        for (int c = 0; c < NIC; ++c) W2f[o][c] = w2[o * NIC + c] * inv;
    }

    float r[4];
#pragma unroll
    for (int i = 0; i < 4; ++i) {
        // conv1 + BN1 + ReLU
        float h1[NIC];
#pragma unroll
        for (int o = 0; o < NIC; ++o) {
            float a = B1f[o];
#pragma unroll
            for (int c = 0; c < NC; ++c) a = fmaf(W1f[o][c], xp[i][c], a);
            h1[o] = fmaxf(a, 0.0f);
        }

        // conv2 + BN2, track channel max for stable softmax
        float h2[NC];
        float mx = -3.4e38f;
#pragma unroll
        for (int o = 0; o < NC; ++o) {
            float a = B2f[o];
#pragma unroll
            for (int c = 0; c < NIC; ++c) a = fmaf(W2f[o][c], h1[c], a);
            h2[o] = a;
            mx = fmaxf(mx, a);
        }

        // softmax over channels fused with weighted channel-sum
        float sum = 0.0f, acc = 0.0f;
#pragma unroll
        for (int o = 0; o < NC; ++o) {
            const float e = __expf(h2[o] - mx);
            sum += e;
            acc = fmaf(e, xp[i][o], acc);
        }
        r[i] = acc * __builtin_amdgcn_rcpf(sum);  // sum in [1,6]; approx rcp ok
    }

    *(float4*)(out + p) = make_float4(r[0], r[1], r[2], r[3]);
}

extern "C" void kernel_launch(void* const* d_in, const int* in_sizes, int n_in,
                              void* d_out, int out_size, void* d_ws, size_t ws_size,
                              hipStream_t stream) {
    const float* x   = (const float*)d_in[0];
    const float* w1  = (const float*)d_in[1];
    const float* b1  = (const float*)d_in[2];
    const float* g1  = (const float*)d_in[3];
    const float* be1 = (const float*)d_in[4];
    const float* m1  = (const float*)d_in[5];
    const float* v1  = (const float*)d_in[6];
    const float* w2  = (const float*)d_in[7];
    const float* b2  = (const float*)d_in[8];
    const float* g2  = (const float*)d_in[9];
    const float* be2 = (const float*)d_in[10];
    const float* m2  = (const float*)d_in[11];
    const float* v2  = (const float*)d_in[12];
    float* out = (float*)d_out;

    // out_size = 32*512*512 = 8,388,608 pixels; 4 pixels/thread
    const int threads = 256;
    const int total4  = out_size / 4;                      // 2,097,152
    const int blocks  = (total4 + threads - 1) / threads;  // 8192

    aff_softmax_kernel<<<blocks, threads, 0, stream>>>(
        x, w1, b1, g1, be1, m1, v1, w2, b2, g2, be2, m2, v2, out);
}